// Round 3
// baseline (473.313 us; speedup 1.0000x reference)
//
#include <hip/hip_runtime.h>
#include <hip/hip_bf16.h>

typedef short bf16x8 __attribute__((ext_vector_type(8)));
typedef float f32x4 __attribute__((ext_vector_type(4)));
typedef __attribute__((address_space(1))) const void gconst_t;
typedef __attribute__((address_space(3))) void lds_t;

#define DEVI __device__ __forceinline__

constexpr int BATCH   = 8192;
constexpr int IN_DIM  = 1024;
constexpr int HID     = 4096;
constexpr int OUT_DIM = 1024;
constexpr int NE      = 3;

// ---- workspace layout (bytes) ----
constexpr size_t XBF_OFF  = 0;                         // x bf16: 16 MB
constexpr size_t W1T_OFF  = 16777216;                  // W1T bf16 [E][HID][IN]: 24 MB
constexpr size_t W2T_OFF  = W1T_OFF + 25165824;        // W2T bf16 [E][OUT][HID]: 24 MB
constexpr size_t H_OFF    = W2T_OFF + 25165824;        // H bf16 grouped rows: 64 MB
constexpr size_t META_OFF = H_OFF + 67108864;          // counts[16], toklist[3*8192]

DEVI unsigned short f2bf(float f) {
  __hip_bfloat16 h = __float2bfloat16(f);
  return *reinterpret_cast<unsigned short*>(&h);
}

// =====================================================================
// Fused preprocessing. LDS capped at 16.6 KB (transpose tile) so all
// block types get ~9 blocks/CU (was 36 KB -> 4/CU -> latency-bound).
//   [0,1024)       router: 8 tokens/block, f32, x via wave-uniform loads
//   [1024,4096)    transpose+cvt W1  (per expert [1024][4096]->[4096][1024])
//   [4096,7168)    transpose+cvt W2  (per expert [4096][1024]->[1024][4096])
//   [7168,7680)    x f32 -> bf16
// =====================================================================
__global__ __launch_bounds__(256) void prep_kernel(
    const float* __restrict__ x, const float* __restrict__ ew1, const float* __restrict__ ew2,
    const float* __restrict__ rw1, const float* __restrict__ rb1,
    const float* __restrict__ rw2, const float* __restrict__ rb2,
    unsigned short* __restrict__ xb, unsigned short* __restrict__ w1t,
    unsigned short* __restrict__ w2t, int* __restrict__ counts, int* __restrict__ toklist) {
  __shared__ float psm[64 * 65];  // 16640 B; router uses first 1048 floats
  const int b = blockIdx.x;
  const int tid = threadIdx.x;

  if (b < 1024) {
    // ---------------- router (f32, bit-identical FMA order to rounds 1-2) ----
    const int t0 = b * 8;
    const int hcol = tid & 127;
    const int g = tid >> 7;                       // wave-uniform (waves 0,1 vs 2,3)
    const float* xrow0 = x + (size_t)(t0 + g * 4) * 1024;
    float acc[4] = {0.f, 0.f, 0.f, 0.f};
    for (int k = 0; k < 1024; k += 4) {
      const float w0 = rw1[(k + 0) * 128 + hcol];
      const float w1v = rw1[(k + 1) * 128 + hcol];
      const float w2v = rw1[(k + 2) * 128 + hcol];
      const float w3v = rw1[(k + 3) * 128 + hcol];
#pragma unroll
      for (int tt = 0; tt < 4; tt++) {
        const float4 xv = *(const float4*)(xrow0 + (size_t)tt * 1024 + k);
        acc[tt] = fmaf(xv.x, w0, acc[tt]);
        acc[tt] = fmaf(xv.y, w1v, acc[tt]);
        acc[tt] = fmaf(xv.z, w2v, acc[tt]);
        acc[tt] = fmaf(xv.w, w3v, acc[tt]);
      }
    }
    const float bb1 = rb1[hcol];
#pragma unroll
    for (int tt = 0; tt < 4; tt++)
      psm[(g * 4 + tt) * 128 + hcol] = fmaxf(acc[tt] + bb1, 0.f);   // rh[8][128]
    __syncthreads();
    float* lg = psm + 1024;   // [8][3]
    if (tid < 24) {
      const int t = tid / 3, e = tid % 3;
      float s = rb2[e];
      for (int j = 0; j < 128; j++) s = fmaf(psm[t * 128 + j], rw2[j * 3 + e], s);
      lg[t * 3 + e] = s;
    }
    __syncthreads();
    if (tid < 8) {
      const float l0 = lg[tid * 3], l1 = lg[tid * 3 + 1], l2 = lg[tid * 3 + 2];
      int sel = 0; float m = l0;
      if (l1 > m) { m = l1; sel = 1; }
      if (l2 > m) { m = l2; sel = 2; }
      const int slot = atomicAdd(&counts[sel], 1);
      toklist[sel * BATCH + slot] = t0 + tid;
    }
  } else if (b < 7168) {
    // ---------------- weight transpose + cvt ----------------
    float (*tile)[65] = (float(*)[65])psm;
    const float* src; unsigned short* dst; int R, C, r0, c0;
    if (b < 4096) {
      const int bb = b - 1024, e = bb / 1024, w = bb % 1024;
      src = ew1 + (size_t)e * 1024 * 4096; dst = w1t + (size_t)e * 4096 * 1024;
      R = 1024; C = 4096; r0 = (w & 15) * 64; c0 = (w >> 4) * 64;
    } else {
      const int bb = b - 4096, e = bb / 1024, w = bb % 1024;
      src = ew2 + (size_t)e * 4096 * 1024; dst = w2t + (size_t)e * 1024 * 4096;
      R = 4096; C = 1024; r0 = (w & 63) * 64; c0 = (w >> 6) * 64;
    }
    const int tr = tid >> 4;
    const int tc = (tid & 15) << 2;
#pragma unroll
    for (int i = 0; i < 4; i++) {
      const int r = tr + i * 16;
      const float4 v = *(const float4*)(src + (size_t)(r0 + r) * C + (c0 + tc));
      tile[r][tc + 0] = v.x; tile[r][tc + 1] = v.y; tile[r][tc + 2] = v.z; tile[r][tc + 3] = v.w;
    }
    __syncthreads();
#pragma unroll
    for (int i = 0; i < 4; i++) {
      const int c = tr + i * 16;
      ushort4 o;
      o.x = f2bf(tile[tc + 0][c]);
      o.y = f2bf(tile[tc + 1][c]);
      o.z = f2bf(tile[tc + 2][c]);
      o.w = f2bf(tile[tc + 3][c]);
      *(ushort4*)(dst + (size_t)(c0 + c) * R + (r0 + tc)) = o;
    }
  } else {
    // ---------------- x -> bf16 ----------------
    const float4* xv4 = (const float4*)x;
    const int total = BATCH * IN_DIM / 4;
    for (int i = (b - 7168) * 256 + tid; i < total; i += 512 * 256) {
      const float4 v = xv4[i];
      ushort4 o;
      o.x = f2bf(v.x); o.y = f2bf(v.y); o.z = f2bf(v.z); o.w = f2bf(v.w);
      ((ushort4*)xb)[i] = o;
    }
  }
}

// =====================================================================
// Grouped bf16 GEMM: BM=256, BK=32, 8 waves (2M x 4N), per-wave out 128xBN/4.
// T3-minimum single-barrier dbuf loop: STAGE(t+1) issued BEFORE ds_read+MFMA
// of tile t; one __syncthreads per K-step drains vmcnt+lgkm (stage landed,
// reads done). Compiler handles fine-grained lgkmcnt between ds_read & MFMA.
// MODE 0: BN=256, K=1024. A = xb gathered, B = W1T[e]. relu(+b1) -> H bf16.
// MODE 1: BN=128, K=4096. A = H grouped,   B = W2T[e]. +b2 -> scatter f32.
// =====================================================================
template <int MODE>
__global__ __launch_bounds__(512, 2) void moe_gemm(
    const unsigned short* __restrict__ Abase, const unsigned short* __restrict__ Ball,
    const float* __restrict__ biasAll, unsigned short* __restrict__ Hout,
    float* __restrict__ Yout, const int* __restrict__ toklist, const int* __restrict__ counts,
    float* __restrict__ tail) {
  constexpr int BN = (MODE == 0) ? 256 : 128;
  constexpr int N  = (MODE == 0) ? HID : OUT_DIM;
  constexpr int K  = (MODE == 0) ? IN_DIM : HID;
  constexpr int NT = K / 32;
  constexpr int NF = BN / 64;          // B frags per wave (4 or 2)
  constexpr int BLOADS = BN / 128;     // global_load_lds per thread for B (2 or 1)

  const int tid = threadIdx.x;
  if (MODE == 0 && blockIdx.x == 0 && blockIdx.y == 0 && tid < NE)
    tail[tid] = (float)counts[tid];

  // flat M-grid -> (expert, m-block)
  const int c0 = counts[0], c1 = counts[1], c2 = counts[2];
  const int mb0 = (c0 + 255) >> 8, mb1 = (c1 + 255) >> 8, mb2 = (c2 + 255) >> 8;
  const int bx = blockIdx.x;
  int e, mblk;
  if (bx < mb0) { e = 0; mblk = bx; }
  else if (bx < mb0 + mb1) { e = 1; mblk = bx - mb0; }
  else if (bx < mb0 + mb1 + mb2) { e = 2; mblk = bx - mb0 - mb1; }
  else return;
  const int cnt = (e == 0) ? c0 : (e == 1) ? c1 : c2;
  const int m0 = mblk * 256;
  const int n0 = blockIdx.y * BN;
  const int off_e = (e > 0 ? c0 : 0) + (e > 1 ? c1 : 0);
  const unsigned short* Bmat = Ball + (size_t)e * ((size_t)N * K);
  const float* bias = biasAll + (size_t)e * N;

  __shared__ unsigned short Ab[2][256 * 32];   // 16 KB per buf
  __shared__ unsigned short Bb[2][BN * 32];    // 16 or 8 KB per buf

  // staging: LDS dest linear o; global source uses swizzled p so that the
  // reader's XOR(addr, (row&3)<<4) recovers logical (row, kslot). Bijective:
  // rows are 64 B; p = o ^ (((o>>6)&3)<<4) flips in-row 16B-slot bits only.
  const unsigned short* asrc[2];
  unsigned aoff[2];
  const unsigned short* bsrc[BLOADS];
  unsigned boff[BLOADS];
#pragma unroll
  for (int l = 0; l < 2; l++) {
    const unsigned o = l * 8192u + (unsigned)tid * 16u;
    const unsigned p = o ^ (((o >> 6) & 3u) << 4);
    const int row = (int)(o >> 6);
    const int kel = (int)((p & 63u) >> 1);
    aoff[l] = o;
    int slot = m0 + row; if (slot > cnt - 1) slot = cnt - 1;
    const size_t arow = (MODE == 0) ? (size_t)toklist[e * BATCH + slot]
                                    : (size_t)(off_e + slot);
    asrc[l] = Abase + arow * K + kel;
  }
#pragma unroll
  for (int l = 0; l < BLOADS; l++) {
    const unsigned o = l * 8192u + (unsigned)tid * 16u;
    const unsigned p = o ^ (((o >> 6) & 3u) << 4);
    const int row = (int)(o >> 6);
    const int kel = (int)((p & 63u) >> 1);
    boff[l] = o;
    bsrc[l] = Bmat + (size_t)(n0 + row) * K + kel;
  }

  f32x4 acc[8][NF];
#pragma unroll
  for (int i = 0; i < 8; i++)
#pragma unroll
    for (int j = 0; j < NF; j++) acc[i][j] = {0.f, 0.f, 0.f, 0.f};

  const int lane = tid & 63;
  const int wave = tid >> 6;
  const int wm = (wave >> 2) * 128;
  const int wn = (wave & 3) * (BN / 4);
  const int fr = lane & 15;
  const int fc = lane >> 4;

  auto STAGE = [&](int buf, int kofs) {
#pragma unroll
    for (int l = 0; l < 2; l++)
      __builtin_amdgcn_global_load_lds((gconst_t*)(asrc[l] + kofs),
                                       (lds_t*)((char*)&Ab[buf][0] + aoff[l]), 16, 0, 0);
#pragma unroll
    for (int l = 0; l < BLOADS; l++)
      __builtin_amdgcn_global_load_lds((gconst_t*)(bsrc[l] + kofs),
                                       (lds_t*)((char*)&Bb[buf][0] + boff[l]), 16, 0, 0);
  };

  STAGE(0, 0);
  __syncthreads();  // drains vmcnt(0): tile 0 in LDS

  for (int t = 0; t < NT; ++t) {
    const int cur = t & 1;
    if (t + 1 < NT) STAGE(cur ^ 1, (t + 1) * 32);  // prefetch: in flight under compute
    bf16x8 af[8], bv[NF];
#pragma unroll
    for (int m = 0; m < 8; m++) {
      const unsigned row = (unsigned)(wm + m * 16 + fr);
      const unsigned addr = ((row << 6) + (unsigned)(fc << 4)) ^ ((row & 3u) << 4);
      af[m] = *(const bf16x8*)((const char*)&Ab[cur][0] + addr);
    }
#pragma unroll
    for (int n = 0; n < NF; n++) {
      const unsigned row = (unsigned)(wn + n * 16 + fr);
      const unsigned addr = ((row << 6) + (unsigned)(fc << 4)) ^ ((row & 3u) << 4);
      bv[n] = *(const bf16x8*)((const char*)&Bb[cur][0] + addr);
    }
    __builtin_amdgcn_s_setprio(1);
#pragma unroll
    for (int m = 0; m < 8; m++)
#pragma unroll
      for (int n = 0; n < NF; n++)
        acc[m][n] = __builtin_amdgcn_mfma_f32_16x16x32_bf16(af[m], bv[n], acc[m][n], 0, 0, 0);
    __builtin_amdgcn_s_setprio(0);
    __syncthreads();  // stage landed (vmcnt 0) + all reads of buf[cur] done
  }

  // epilogue: C/D layout col=lane&15, row=(lane>>4)*4+reg  [HW-verified m89/m91]
  const int crow = (lane >> 4) * 4;
  const int ccol = lane & 15;
#pragma unroll
  for (int mi = 0; mi < 8; mi++) {
#pragma unroll
    for (int r = 0; r < 4; r++) {
      const int slot = m0 + wm + mi * 16 + crow + r;
      if (slot >= cnt) continue;
      if (MODE == 0) {
        unsigned short* hrow = Hout + (size_t)(off_e + slot) * HID;
#pragma unroll
        for (int ni = 0; ni < NF; ni++) {
          const int n = n0 + wn + ni * 16 + ccol;
          const float v = acc[mi][ni][r] + bias[n];
          hrow[n] = f2bf(fmaxf(v, 0.f));
        }
      } else {
        const int tok = toklist[e * BATCH + slot];
        float* yrow = Yout + (size_t)tok * OUT_DIM;
#pragma unroll
        for (int ni = 0; ni < NF; ni++) {
          const int n = n0 + wn + ni * 16 + ccol;
          yrow[n] = acc[mi][ni][r] + bias[n];
        }
      }
    }
  }
}

extern "C" void kernel_launch(void* const* d_in, const int* in_sizes, int n_in,
                              void* d_out, int out_size, void* d_ws, size_t ws_size,
                              hipStream_t stream) {
  const float* x   = (const float*)d_in[0];
  const float* rw1 = (const float*)d_in[1];
  const float* rb1 = (const float*)d_in[2];
  const float* rw2 = (const float*)d_in[3];
  const float* rb2 = (const float*)d_in[4];
  const float* ew1 = (const float*)d_in[5];
  const float* eb1 = (const float*)d_in[6];
  const float* ew2 = (const float*)d_in[7];
  const float* eb2 = (const float*)d_in[8];
  float* out = (float*)d_out;

  char* ws = (char*)d_ws;
  unsigned short* xb  = (unsigned short*)(ws + XBF_OFF);
  unsigned short* w1t = (unsigned short*)(ws + W1T_OFF);
  unsigned short* w2t = (unsigned short*)(ws + W2T_OFF);
  unsigned short* h   = (unsigned short*)(ws + H_OFF);
  int* counts  = (int*)(ws + META_OFF);
  int* toklist = counts + 16;
  float* tail = out + (size_t)BATCH * OUT_DIM;

  hipMemsetAsync(counts, 0, 64, stream);
  prep_kernel<<<7680, 256, 0, stream>>>(x, ew1, ew2, rw1, rb1, rw2, rb2,
                                        xb, w1t, w2t, counts, toklist);
  moe_gemm<0><<<dim3(34, 16), 512, 0, stream>>>(xb, w1t, eb1, h, nullptr, toklist, counts, tail);
  moe_gemm<1><<<dim3(34, 8), 512, 0, stream>>>(h, w2t, eb2, nullptr, out, toklist, counts, tail);
}

// Round 4
// 351.909 us; speedup vs baseline: 1.3450x; 1.3450x over previous
//
#include <hip/hip_runtime.h>
#include <hip/hip_bf16.h>

typedef short bf16x8 __attribute__((ext_vector_type(8)));
typedef float f32x4 __attribute__((ext_vector_type(4)));
typedef __attribute__((address_space(1))) const void gconst_t;
typedef __attribute__((address_space(3))) void lds_t;

#define DEVI __device__ __forceinline__

constexpr int BATCH   = 8192;
constexpr int IN_DIM  = 1024;
constexpr int HID     = 4096;
constexpr int OUT_DIM = 1024;
constexpr int NE      = 3;

// ---- workspace layout (bytes) ----
constexpr size_t XBF_OFF  = 0;                         // x bf16: 16 MB
constexpr size_t W1T_OFF  = 16777216;                  // W1T bf16 [E][HID][IN]: 24 MB
constexpr size_t W2T_OFF  = W1T_OFF + 25165824;        // W2T bf16 [E][OUT][HID]: 24 MB
constexpr size_t H_OFF    = W2T_OFF + 25165824;        // H bf16 grouped rows: 64 MB
constexpr size_t META_OFF = H_OFF + 67108864;          // counts[16], toklist[3*8192]

DEVI unsigned short f2bf(float f) {
  __hip_bfloat16 h = __float2bfloat16(f);
  return *reinterpret_cast<unsigned short*>(&h);
}

// =====================================================================
// Fused preprocessing, 20.7 KB LDS for all branches -> 7 blocks/CU.
//   [0,1024)       router: 8 tok/block, f32, x staged in LDS in 2 k-passes
//   [1024,7168)    transpose+cvt W1 / W2
//   [7168,7680)    x f32 -> bf16
// =====================================================================
__global__ __launch_bounds__(256) void prep_kernel(
    const float* __restrict__ x, const float* __restrict__ ew1, const float* __restrict__ ew2,
    const float* __restrict__ rw1, const float* __restrict__ rb1,
    const float* __restrict__ rw2, const float* __restrict__ rb2,
    unsigned short* __restrict__ xb, unsigned short* __restrict__ w1t,
    unsigned short* __restrict__ w2t, int* __restrict__ counts, int* __restrict__ toklist) {
  __shared__ float smem[5184];  // router: xs[8*512]+rh[8*132]+lg; transpose: tile[64][65]
  const int b = blockIdx.x;
  const int tid = threadIdx.x;

  if (b < 1024) {
    // ---------------- router (f32; k ascends 0..1023, order == rounds 1-3) ----
    const int t0 = b * 8;
    float* xs = smem;             // [8][512]
    float* rh = smem + 4096;      // [8][132] padded stride
    const int hcol = tid & 127;
    const int g = tid >> 7;       // tokens g*4 .. g*4+3
    float acc[4] = {0.f, 0.f, 0.f, 0.f};
    for (int half = 0; half < 2; half++) {
      __syncthreads();  // prior pass reads complete
      {
        const float* xsrc = x + (size_t)t0 * 1024 + half * 512;
        for (int i = tid; i < 1024; i += 256) {
          const int tok = i >> 7, c4 = i & 127;
          *(float4*)&xs[tok * 512 + c4 * 4] =
              *(const float4*)(xsrc + (size_t)tok * 1024 + c4 * 4);
        }
      }
      __syncthreads();
      const int kbase = half * 512;
      for (int k = 0; k < 512; k += 4) {
        const float w0 = rw1[(kbase + k + 0) * 128 + hcol];
        const float w1v = rw1[(kbase + k + 1) * 128 + hcol];
        const float w2v = rw1[(kbase + k + 2) * 128 + hcol];
        const float w3v = rw1[(kbase + k + 3) * 128 + hcol];
#pragma unroll
        for (int tt = 0; tt < 4; tt++) {
          const float4 xv = *(const float4*)&xs[(g * 4 + tt) * 512 + k];
          acc[tt] = fmaf(xv.x, w0, acc[tt]);
          acc[tt] = fmaf(xv.y, w1v, acc[tt]);
          acc[tt] = fmaf(xv.z, w2v, acc[tt]);
          acc[tt] = fmaf(xv.w, w3v, acc[tt]);
        }
      }
    }
    const float bb1 = rb1[hcol];
#pragma unroll
    for (int tt = 0; tt < 4; tt++)
      rh[(g * 4 + tt) * 132 + hcol] = fmaxf(acc[tt] + bb1, 0.f);
    __syncthreads();
    float* lg = smem + 4096 + 8 * 132;  // [8][3]
    if (tid < 24) {
      const int t = tid / 3, e = tid % 3;
      float s = rb2[e];
      for (int j = 0; j < 128; j++) s = fmaf(rh[t * 132 + j], rw2[j * 3 + e], s);
      lg[t * 3 + e] = s;
    }
    __syncthreads();
    if (tid < 8) {
      const float l0 = lg[tid * 3], l1 = lg[tid * 3 + 1], l2 = lg[tid * 3 + 2];
      int sel = 0; float m = l0;
      if (l1 > m) { m = l1; sel = 1; }
      if (l2 > m) { m = l2; sel = 2; }
      const int slot = atomicAdd(&counts[sel], 1);
      toklist[sel * BATCH + slot] = t0 + tid;
    }
  } else if (b < 7168) {
    // ---------------- weight transpose + cvt ----------------
    float (*tile)[65] = (float(*)[65])smem;
    const float* src; unsigned short* dst; int R, C, r0, c0;
    if (b < 4096) {
      const int bb = b - 1024, e = bb / 1024, w = bb % 1024;
      src = ew1 + (size_t)e * 1024 * 4096; dst = w1t + (size_t)e * 4096 * 1024;
      R = 1024; C = 4096; r0 = (w & 15) * 64; c0 = (w >> 4) * 64;
    } else {
      const int bb = b - 4096, e = bb / 1024, w = bb % 1024;
      src = ew2 + (size_t)e * 4096 * 1024; dst = w2t + (size_t)e * 1024 * 4096;
      R = 4096; C = 1024; r0 = (w & 63) * 64; c0 = (w >> 6) * 64;
    }
    const int tr = tid >> 4;
    const int tc = (tid & 15) << 2;
#pragma unroll
    for (int i = 0; i < 4; i++) {
      const int r = tr + i * 16;
      const float4 v = *(const float4*)(src + (size_t)(r0 + r) * C + (c0 + tc));
      tile[r][tc + 0] = v.x; tile[r][tc + 1] = v.y; tile[r][tc + 2] = v.z; tile[r][tc + 3] = v.w;
    }
    __syncthreads();
#pragma unroll
    for (int i = 0; i < 4; i++) {
      const int c = tr + i * 16;
      ushort4 o;
      o.x = f2bf(tile[tc + 0][c]);
      o.y = f2bf(tile[tc + 1][c]);
      o.z = f2bf(tile[tc + 2][c]);
      o.w = f2bf(tile[tc + 3][c]);
      *(ushort4*)(dst + (size_t)(c0 + c) * R + (r0 + tc)) = o;
    }
  } else {
    // ---------------- x -> bf16 ----------------
    const float4* xv4 = (const float4*)x;
    const int total = BATCH * IN_DIM / 4;
    for (int i = (b - 7168) * 256 + tid; i < total; i += 512 * 256) {
      const float4 v = xv4[i];
      ushort4 o;
      o.x = f2bf(v.x); o.y = f2bf(v.y); o.z = f2bf(v.z); o.w = f2bf(v.w);
      ((ushort4*)xb)[i] = o;
    }
  }
}

// =====================================================================
// Grouped bf16 GEMM: BM=128, BN=256, BK=32, 8 waves (2M x 4N), 64x64/wave.
// Counted-vmcnt pipeline: NBUF=3, depth D=2, one s_barrier per K-step,
// steady-state s_waitcnt vmcnt(3) (= (D-1)*LPT, LPT=3), vmcnt(0) only at
// the final iteration. Buffer (t+2)%3 was last read at iter t-1; every
// wave's iter-t barrier follows its iter-(t-1) ds_reads => no WAR race.
// MODE 0: K=1024, A = xb gathered via toklist, relu(+b1) -> H bf16 grouped.
// MODE 1: K=4096, A = H grouped, +b2 -> scatter f32 rows of d_out.
// =====================================================================
template <int MODE>
__global__ __launch_bounds__(512, 2) void moe_gemm(
    const unsigned short* __restrict__ Abase, const unsigned short* __restrict__ Ball,
    const float* __restrict__ biasAll, unsigned short* __restrict__ Hout,
    float* __restrict__ Yout, const int* __restrict__ toklist, const int* __restrict__ counts,
    float* __restrict__ tail) {
  constexpr int N  = (MODE == 0) ? HID : OUT_DIM;
  constexpr int K  = (MODE == 0) ? IN_DIM : HID;
  constexpr int NT = K / 32;

  const int tid = threadIdx.x;
  if (MODE == 0 && blockIdx.x == 0 && blockIdx.y == 0 && tid < NE)
    tail[tid] = (float)counts[tid];

  // flat M-grid -> (expert, m-block), BM=128
  const int c0 = counts[0], c1 = counts[1], c2 = counts[2];
  const int mb0 = (c0 + 127) >> 7, mb1 = (c1 + 127) >> 7, mb2 = (c2 + 127) >> 7;
  const int bx = blockIdx.x;
  int e, mblk;
  if (bx < mb0) { e = 0; mblk = bx; }
  else if (bx < mb0 + mb1) { e = 1; mblk = bx - mb0; }
  else if (bx < mb0 + mb1 + mb2) { e = 2; mblk = bx - mb0 - mb1; }
  else return;
  const int cnt = (e == 0) ? c0 : (e == 1) ? c1 : c2;
  const int m0 = mblk * 128;
  const int n0 = blockIdx.y * 256;
  const int off_e = (e > 0 ? c0 : 0) + (e > 1 ? c1 : 0);
  const unsigned short* Bmat = Ball + (size_t)e * ((size_t)N * K);
  const float* bias = biasAll + (size_t)e * N;

  __shared__ unsigned short Ab[3][128 * 32];   // 8 KB per buf
  __shared__ unsigned short Bb[3][256 * 32];   // 16 KB per buf   (total 72 KB)

  // staging: LDS dest linear o; global source pre-swizzled p so readers'
  // XOR(addr, (row&3)<<4) recovers logical (row, kslot). Rows are 64 B.
  const unsigned short* asrc;
  const unsigned short* bsrc[2];
  unsigned aoff, boff[2];
  {
    const unsigned o = (unsigned)tid * 16u;
    const unsigned p = o ^ (((o >> 6) & 3u) << 4);
    const int row = (int)(o >> 6);             // 0..127
    const int kel = (int)((p & 63u) >> 1);
    aoff = o;
    int slot = m0 + row; if (slot > cnt - 1) slot = cnt - 1;
    const size_t arow = (MODE == 0) ? (size_t)toklist[e * BATCH + slot]
                                    : (size_t)(off_e + slot);
    asrc = Abase + arow * K + kel;
  }
#pragma unroll
  for (int l = 0; l < 2; l++) {
    const unsigned o = l * 8192u + (unsigned)tid * 16u;
    const unsigned p = o ^ (((o >> 6) & 3u) << 4);
    const int row = (int)(o >> 6);             // 0..255
    const int kel = (int)((p & 63u) >> 1);
    boff[l] = o;
    bsrc[l] = Bmat + (size_t)(n0 + row) * K + kel;
  }

  f32x4 acc[4][4];
#pragma unroll
  for (int i = 0; i < 4; i++)
#pragma unroll
    for (int j = 0; j < 4; j++) acc[i][j] = {0.f, 0.f, 0.f, 0.f};

  const int lane = tid & 63;
  const int wave = tid >> 6;
  const int wm = (wave >> 2) * 64;
  const int wn = (wave & 3) * 64;
  const int fr = lane & 15;
  const int fc = lane >> 4;

  auto STAGE = [&](int buf, int kofs) {
    __builtin_amdgcn_global_load_lds((gconst_t*)(asrc + kofs),
                                     (lds_t*)((char*)&Ab[buf][0] + aoff), 16, 0, 0);
#pragma unroll
    for (int l = 0; l < 2; l++)
      __builtin_amdgcn_global_load_lds((gconst_t*)(bsrc[l] + kofs),
                                       (lds_t*)((char*)&Bb[buf][0] + boff[l]), 16, 0, 0);
  };

  STAGE(0, 0);
  STAGE(1, 32);

  int cur = 0;
  for (int t = 0; t < NT; ++t) {
    if (t + 1 < NT) asm volatile("s_waitcnt vmcnt(3)" ::: "memory");
    else            asm volatile("s_waitcnt vmcnt(0)" ::: "memory");
    __builtin_amdgcn_sched_barrier(0);
    __builtin_amdgcn_s_barrier();          // all waves' stage-t landed
    __builtin_amdgcn_sched_barrier(0);
    bf16x8 af[4], bv[4];
#pragma unroll
    for (int m = 0; m < 4; m++) {
      const unsigned row = (unsigned)(wm + m * 16 + fr);
      const unsigned addr = ((row << 6) + (unsigned)(fc << 4)) ^ ((row & 3u) << 4);
      af[m] = *(const bf16x8*)((const char*)&Ab[cur][0] + addr);
    }
#pragma unroll
    for (int n = 0; n < 4; n++) {
      const unsigned row = (unsigned)(wn + n * 16 + fr);
      const unsigned addr = ((row << 6) + (unsigned)(fc << 4)) ^ ((row & 3u) << 4);
      bv[n] = *(const bf16x8*)((const char*)&Bb[cur][0] + addr);
    }
    asm volatile("s_waitcnt lgkmcnt(0)" ::: "memory");
    __builtin_amdgcn_sched_barrier(0);     // rule #18: pin MFMA after the wait
    __builtin_amdgcn_s_setprio(1);
#pragma unroll
    for (int m = 0; m < 4; m++)
#pragma unroll
      for (int n = 0; n < 4; n++)
        acc[m][n] = __builtin_amdgcn_mfma_f32_16x16x32_bf16(af[m], bv[n], acc[m][n], 0, 0, 0);
    __builtin_amdgcn_s_setprio(0);
    if (t + 2 < NT) {
      const int nb = (cur + 2 >= 3) ? cur - 1 : cur + 2;
      STAGE(nb, (t + 2) * 32);
    }
    cur = (cur + 1 == 3) ? 0 : cur + 1;
  }

  // epilogue: C/D layout col=lane&15, row=(lane>>4)*4+reg  [HW-verified m89/m91]
  const int crow = (lane >> 4) * 4;
  const int ccol = lane & 15;
#pragma unroll
  for (int mi = 0; mi < 4; mi++) {
#pragma unroll
    for (int r = 0; r < 4; r++) {
      const int slot = m0 + wm + mi * 16 + crow + r;
      if (slot >= cnt) continue;
      if (MODE == 0) {
        unsigned short* hrow = Hout + (size_t)(off_e + slot) * HID;
#pragma unroll
        for (int ni = 0; ni < 4; ni++) {
          const int n = n0 + wn + ni * 16 + ccol;
          const float v = acc[mi][ni][r] + bias[n];
          hrow[n] = f2bf(fmaxf(v, 0.f));
        }
      } else {
        const int tok = toklist[e * BATCH + slot];
        float* yrow = Yout + (size_t)tok * OUT_DIM;
#pragma unroll
        for (int ni = 0; ni < 4; ni++) {
          const int n = n0 + wn + ni * 16 + ccol;
          yrow[n] = acc[mi][ni][r] + bias[n];
        }
      }
    }
  }
}

extern "C" void kernel_launch(void* const* d_in, const int* in_sizes, int n_in,
                              void* d_out, int out_size, void* d_ws, size_t ws_size,
                              hipStream_t stream) {
  const float* x   = (const float*)d_in[0];
  const float* rw1 = (const float*)d_in[1];
  const float* rb1 = (const float*)d_in[2];
  const float* rw2 = (const float*)d_in[3];
  const float* rb2 = (const float*)d_in[4];
  const float* ew1 = (const float*)d_in[5];
  const float* eb1 = (const float*)d_in[6];
  const float* ew2 = (const float*)d_in[7];
  const float* eb2 = (const float*)d_in[8];
  float* out = (float*)d_out;

  char* ws = (char*)d_ws;
  unsigned short* xb  = (unsigned short*)(ws + XBF_OFF);
  unsigned short* w1t = (unsigned short*)(ws + W1T_OFF);
  unsigned short* w2t = (unsigned short*)(ws + W2T_OFF);
  unsigned short* h   = (unsigned short*)(ws + H_OFF);
  int* counts  = (int*)(ws + META_OFF);
  int* toklist = counts + 16;
  float* tail = out + (size_t)BATCH * OUT_DIM;

  hipMemsetAsync(counts, 0, 64, stream);
  prep_kernel<<<7680, 256, 0, stream>>>(x, ew1, ew2, rw1, rb1, rw2, rb2,
                                        xb, w1t, w2t, counts, toklist);
  moe_gemm<0><<<dim3(66, 16), 512, 0, stream>>>(xb, w1t, eb1, h, nullptr, toklist, counts, tail);
  moe_gemm<1><<<dim3(66, 4), 512, 0, stream>>>(h, w2t, eb2, nullptr, out, toklist, counts, tail);
}